// Round 12
// baseline (419.279 us; speedup 1.0000x reference)
//
#include <hip/hip_runtime.h>
#include <stdint.h>

// Problem constants
#define BB 16384
#define DD 1024
#define HH 1024
#define OO 256
#define CC 8

typedef unsigned short u16;
typedef __attribute__((ext_vector_type(4))) unsigned short u16x4;
typedef __attribute__((ext_vector_type(8))) short bf16x8;
typedef __attribute__((ext_vector_type(4))) float f32x4;

__device__ __forceinline__ u16 f2bf(float f) {
    union { float f; uint32_t u; } v; v.f = f;
    const uint32_t u = v.u;
    return (u16)((u + 0x7FFFu + ((u >> 16) & 1u)) >> 16);  // RNE
}

// async global->LDS, 16B per lane (dest must be wave-uniform base + lane*16)
#define GLDS16(g, l)                                                                   \
    __builtin_amdgcn_global_load_lds((const __attribute__((address_space(1))) void*)(g), \
                                     (__attribute__((address_space(3))) void*)(l), 16, 0, 0)

// ---------------------------------------------------------------------------
// Transpose fp32 [nmat][R][Cc] -> bf16 [nmat][Cc][R]  (W -> W^T, K-contiguous)
// ---------------------------------------------------------------------------
__global__ __launch_bounds__(256)
void transpose_bf16_kernel(const float* __restrict__ src, u16* __restrict__ dst,
                           int R, int Cc)
{
    __shared__ float t[32][33];
    const int tid = threadIdx.x;
    const int mat = blockIdx.z;
    const int r0 = blockIdx.y * 32, c0 = blockIdx.x * 32;
    {
        const int rr = tid >> 3, c4 = (tid & 7) * 4;
        const float4 v = *(const float4*)(src + ((size_t)mat * R + r0 + rr) * Cc + c0 + c4);
        t[rr][c4 + 0] = v.x; t[rr][c4 + 1] = v.y; t[rr][c4 + 2] = v.z; t[rr][c4 + 3] = v.w;
    }
    __syncthreads();
    {
        const int cc = tid >> 3, k4 = (tid & 7) * 4;
        u16x4 o;
        o[0] = f2bf(t[k4 + 0][cc]);
        o[1] = f2bf(t[k4 + 1][cc]);
        o[2] = f2bf(t[k4 + 2][cc]);
        o[3] = f2bf(t[k4 + 3][cc]);
        *(u16x4*)(dst + ((size_t)mat * Cc + c0 + cc) * R + r0 + k4) = o;
    }
}

// ---------------------------------------------------------------------------
// Logits (fp32, exact routing) + x -> bf16 + per-block class histogram.
// ---------------------------------------------------------------------------
__global__ __launch_bounds__(256)
void logits_kernel(const float* __restrict__ x, const float* __restrict__ Wc,
                   const float* __restrict__ bc, float* __restrict__ logits_out,
                   u16* __restrict__ x_bf16, int* __restrict__ class_idx,
                   int* __restrict__ hist)
{
    __shared__ float WcT[CC][DD];  // 32 KB, transposed classifier
    __shared__ int clsarr[16];
    const int tid = threadIdx.x;
    #pragma unroll
    for (int j = 0; j < 8; ++j) {
        const int f = tid + 256 * j;                 // float4 index into Wc [D][C]
        const float4 v = ((const float4*)Wc)[f];
        const int d = f >> 1, c = (f & 1) * 4;       // 4 elems share d (C=8)
        WcT[c + 0][d] = v.x; WcT[c + 1][d] = v.y; WcT[c + 2][d] = v.z; WcT[c + 3][d] = v.w;
    }
    __syncthreads();

    const int lane = tid & 63, wv = tid >> 6;
    const int row0 = blockIdx.x * 16 + wv * 4;

    float acc[4][8];
    #pragma unroll
    for (int r = 0; r < 4; ++r)
        #pragma unroll
        for (int c = 0; c < 8; ++c) acc[r][c] = 0.f;

    #pragma unroll
    for (int p = 0; p < 2; ++p) {
        float4 xv[2][4];
        #pragma unroll
        for (int rr = 0; rr < 2; ++rr) {
            const float4* xr = (const float4*)(x + (size_t)(row0 + 2 * p + rr) * DD);
            #pragma unroll
            for (int j = 0; j < 4; ++j) xv[rr][j] = xr[lane + 64 * j];
        }
        #pragma unroll
        for (int rr = 0; rr < 2; ++rr) {
            u16* xb = x_bf16 + (size_t)(row0 + 2 * p + rr) * DD;
            #pragma unroll
            for (int j = 0; j < 4; ++j) {
                const float4 v = xv[rr][j];
                u16x4 o; o[0] = f2bf(v.x); o[1] = f2bf(v.y); o[2] = f2bf(v.z); o[3] = f2bf(v.w);
                *(u16x4*)(xb + 4 * (lane + 64 * j)) = o;
            }
        }
        #pragma unroll
        for (int j = 0; j < 4; ++j) {
            const int f = lane + 64 * j;
            #pragma unroll
            for (int c = 0; c < 8; ++c) {
                const float4 w = *(const float4*)&WcT[c][4 * f];
                #pragma unroll
                for (int rr = 0; rr < 2; ++rr)
                    acc[2 * p + rr][c] += xv[rr][j].x * w.x + xv[rr][j].y * w.y
                                        + xv[rr][j].z * w.z + xv[rr][j].w * w.w;
            }
        }
    }

    #pragma unroll
    for (int off = 8; off < 64; off <<= 1)
        #pragma unroll
        for (int r = 0; r < 4; ++r)
            #pragma unroll
            for (int c = 0; c < 8; ++c)
                acc[r][c] += __shfl_xor(acc[r][c], off, 64);

    const int cls = lane >> 3;
    const float bcv = bc[cls];
    float s[4];
    #pragma unroll
    for (int r = 0; r < 4; ++r) {
        float v = acc[r][0];
        #pragma unroll
        for (int c = 1; c < 8; ++c) v = (cls == c) ? acc[r][c] : v;
        s[r] = v;
    }
    #pragma unroll
    for (int off = 1; off < 8; off <<= 1)
        #pragma unroll
        for (int r = 0; r < 4; ++r) s[r] += __shfl_xor(s[r], off, 64);
    #pragma unroll
    for (int r = 0; r < 4; ++r) s[r] += bcv;

    #pragma unroll
    for (int r = 0; r < 4; ++r)
        if ((lane & 7) == 0) logits_out[(size_t)(row0 + r) * CC + cls] = s[r];

    int idx[4] = {cls, cls, cls, cls};
    #pragma unroll
    for (int off = 8; off < 64; off <<= 1) {
        #pragma unroll
        for (int r = 0; r < 4; ++r) {
            const float ov = __shfl_xor(s[r], off, 64);
            const int oi = __shfl_xor(idx[r], off, 64);
            const bool take = (ov > s[r]) || (ov == s[r] && oi < idx[r]);
            s[r] = take ? ov : s[r];
            idx[r] = take ? oi : idx[r];
        }
    }
    if (lane == 0) {
        #pragma unroll
        for (int r = 0; r < 4; ++r) {
            class_idx[row0 + r] = idx[r];
            clsarr[wv * 4 + r] = idx[r];
        }
    }
    __syncthreads();
    if (tid < 64) {
        const int myc = (tid < 16) ? clsarr[tid] : -1;
        int h = 0;
        #pragma unroll
        for (int cc = 0; cc < 8; ++cc) {
            const int p = __popcll(__ballot(myc == cc));
            h = (tid == cc) ? p : h;
        }
        if (tid < 8) hist[blockIdx.x * 8 + tid] = h;
    }
}

// ---------------------------------------------------------------------------
// Single-block scan: per-class totals -> padded offsets (256-granular) +
// per-block scatter bases.
// ---------------------------------------------------------------------------
__global__ __launch_bounds__(256)
void scan_kernel(const int* __restrict__ hist, int* __restrict__ offsets,
                 int* __restrict__ bb)
{
    const int t = threadIdx.x, c = t >> 5, g = t & 31;
    int sum = 0;
    #pragma unroll 4
    for (int i = 0; i < 32; ++i) sum += hist[(g * 32 + i) * 8 + c];
    int inc = sum;
    #pragma unroll
    for (int d = 1; d < 32; d <<= 1) {
        const int v = __shfl_up(inc, d, 32);
        if (g >= d) inc += v;
    }
    __shared__ int tot[8], offL[9];
    if (g == 31) tot[c] = inc;
    __syncthreads();
    if (t == 0) {
        int o = 0; offL[0] = 0; offsets[0] = 0;
        #pragma unroll
        for (int c8 = 0; c8 < 8; ++c8) {
            o += (tot[c8] + 255) & ~255;          // pad to 256 (BM of layer GEMMs)
            offL[c8 + 1] = o; offsets[c8 + 1] = o;
        }
    }
    __syncthreads();
    int base = offL[c] + (inc - sum);
    #pragma unroll 4
    for (int i = 0; i < 32; ++i) {
        const int b = g * 32 + i;
        bb[b * 8 + c] = base;
        base += hist[b * 8 + c];
    }
}

// ---------------------------------------------------------------------------
// Scatter row ids into per-class segments — atomic-free via ballot ranking.
// ---------------------------------------------------------------------------
__global__ __launch_bounds__(256)
void scatter_kernel(const int* __restrict__ class_idx, const int* __restrict__ bb,
                    int* __restrict__ rowidx)
{
    const int r = blockIdx.x * 256 + threadIdx.x;
    const int c = class_idx[r];
    const int lane = threadIdx.x & 63;
    const int gl = lane & ~15;
    const unsigned long long before = (1ull << lane) - (1ull << gl);
    int rank = 0;
    #pragma unroll
    for (int cc = 0; cc < 8; ++cc) {
        const unsigned long long m = __ballot(c == cc);
        const int p = __popcll(m & before);
        rank = (c == cc) ? p : rank;
    }
    rowidx[bb[(r >> 4) * 8 + c] + rank] = r;
}

// ---------------------------------------------------------------------------
// R12 main GEMM (layers 1-3): FAT-WAVE x R4-EXACT-SCHEDULE (the untested
// quadrant). BM=256, BN=128, BK=32, 256 thr / 4 waves (2Mx2N), wave=128x64
// (acc[8][4]): 2x FLOPs/block and 0.375 KB LDS-read/MFMA vs R4's 0.5.
// Schedule: byte-for-byte R4 — STAGE(next buf); COMPUTE(cur); __syncthreads()
// — no raw barriers, no counted vmcnt (those regressed 4x: R5-R10).
// LDS 48 KB dbuf. Swizzle: chunk^((row>>1)&3) both sides (R6/R7-validated,
// measured 0 conflicts). T1 XCD-chunked grid (576 blocks, %8=0), T5 setprio.
// ---------------------------------------------------------------------------
#define MF(a, b, c) __builtin_amdgcn_mfma_f32_16x16x32_bf16((a), (b), (c), 0, 0, 0)
#define ASZ 8192   // u16 per A buffer (256x32)
#define BSZ 4096   // u16 per B buffer (128x32)

template<bool GATHER_A>
__global__ __launch_bounds__(256)
void gemm_kernel(const u16* __restrict__ Abase, const u16* __restrict__ Wbase,
                 size_t wclass_stride, const float* __restrict__ bias_base,
                 int bias_stride, const int* __restrict__ offsets,
                 const int* __restrict__ rowidx, u16* __restrict__ Hout)
{
    __shared__ u16 sA[2 * ASZ];   // 32 KB
    __shared__ u16 sB[2 * BSZ];   // 16 KB
    const int tid = threadIdx.x;

    // XCD-chunked bijective swizzle (grid % 8 == 0), n0-inner
    const int bid = blockIdx.x;
    const int wg = (bid & 7) * ((int)gridDim.x >> 3) + (bid >> 3);
    const int m0 = (wg >> 3) * 256;
    const int n0 = (wg & 7) * 128;
    if (m0 >= offsets[CC]) return;
    int c = 0;
    while (m0 >= offsets[c + 1]) ++c;          // offsets are 256-multiples

    const u16* const Wcl = Wbase + (size_t)c * wclass_stride;

    // ---- staging precompute: 6 chunks/thread/K-tile (4 A + 2 B).
    // A: chunk n = tid + 256*j, n in [0,1024): row = n>>2, chunk = n&3.
    // B: chunk n = tid + 256*(j-4), n in [0,512): row = n>>2.
    // swizzle: LDS linear at n*8; global source column (n&3)^((row>>1)&3).
    const u16* gsrc[6];
    int dn[6];
    #pragma unroll
    for (int j = 0; j < 6; ++j) {
        if (j < 4) {
            const int n = tid + 256 * j;
            const int row = n >> 2;
            const int logc = (n & 3) ^ ((row >> 1) & 3);
            int grow = m0 + row;
            if (GATHER_A) { const int g = rowidx[grow]; grow = (g < 0) ? 0 : g; }
            gsrc[j] = Abase + (size_t)grow * 1024 + logc * 8;
            dn[j] = n * 8;
        } else {
            const int n = tid + 256 * (j - 4);
            const int row = n >> 2;
            const int logc = (n & 3) ^ ((row >> 1) & 3);
            gsrc[j] = Wcl + (size_t)(n0 + row) * 1024 + logc * 8;
            dn[j] = n * 8;
        }
    }

#define STAGE(SB, KT)                                                     \
    { GLDS16(gsrc[0] + (KT) * 32, sA + (SB) * ASZ + dn[0]);               \
      GLDS16(gsrc[1] + (KT) * 32, sA + (SB) * ASZ + dn[1]);               \
      GLDS16(gsrc[2] + (KT) * 32, sA + (SB) * ASZ + dn[2]);               \
      GLDS16(gsrc[3] + (KT) * 32, sA + (SB) * ASZ + dn[3]);               \
      GLDS16(gsrc[4] + (KT) * 32, sB + (SB) * BSZ + dn[4]);               \
      GLDS16(gsrc[5] + (KT) * 32, sB + (SB) * BSZ + dn[5]); }

    // ---- fragment read bases (swizzled): frag row = base + mi*16 + lr,
    // (row>>1)&3 == (lr>>1)&3 since base is a multiple of 16.
    const int wv = tid >> 6, ln = tid & 63;
    const int wm = wv >> 1, wn = wv & 1;        // 2M x 2N wave grid
    const int lr = ln & 15, lg = ln >> 4;
    const int pc = (lg ^ ((lr >> 1) & 3)) * 8;  // swizzled 16B-chunk offset
    const u16* const fA = sA + (wm * 128 + lr) * 32 + pc;  // + mi*512 + buf*ASZ
    const u16* const fB = sB + (wn * 64 + lr) * 32 + pc;   // + ni*512 + buf*BSZ

    f32x4 acc[8][4];
    #pragma unroll
    for (int i = 0; i < 8; ++i)
        #pragma unroll
        for (int j = 0; j < 4; ++j)
            acc[i][j] = (f32x4){0.f, 0.f, 0.f, 0.f};

#define COMPUTE(SB)                                                       \
    {                                                                     \
        bf16x8 bfr[4];                                                    \
        _Pragma("unroll")                                                 \
        for (int ni = 0; ni < 4; ++ni)                                    \
            bfr[ni] = *(const bf16x8*)(fB + (SB) * BSZ + ni * 512);       \
        __builtin_amdgcn_s_setprio(1);                                    \
        _Pragma("unroll")                                                 \
        for (int mi = 0; mi < 8; ++mi) {                                  \
            const bf16x8 a = *(const bf16x8*)(fA + (SB) * ASZ + mi * 512);\
            acc[mi][0] = MF(a, bfr[0], acc[mi][0]);                       \
            acc[mi][1] = MF(a, bfr[1], acc[mi][1]);                       \
            acc[mi][2] = MF(a, bfr[2], acc[mi][2]);                       \
            acc[mi][3] = MF(a, bfr[3], acc[mi][3]);                       \
        }                                                                 \
        __builtin_amdgcn_s_setprio(0);                                    \
    }

    // prologue: tile 0 -> buf 0
    STAGE(0, 0);
    __syncthreads();
    // 32 K-tiles; stage t+1 into other buf, compute t, sync (R4 schedule)
    for (int t = 0; t < 30; t += 2) {
        STAGE(1, t + 1); COMPUTE(0); __syncthreads();
        STAGE(0, t + 2); COMPUTE(1); __syncthreads();
    }
    STAGE(1, 31); COMPUTE(0); __syncthreads();
    COMPUTE(1);

#undef COMPUTE
#undef STAGE

    // epilogue: C/D layout col=lane&15, row=(lane>>4)*4+reg; bias + ReLU
    const float* bp = bias_base + (size_t)c * bias_stride + n0 + wn * 64 + lr;
    #pragma unroll
    for (int ni = 0; ni < 4; ++ni) {
        const float bv = bp[ni * 16];
        const int col = n0 + wn * 64 + ni * 16 + lr;
        #pragma unroll
        for (int mi = 0; mi < 8; ++mi) {
            const int rb = m0 + wm * 128 + mi * 16 + lg * 4;
            #pragma unroll
            for (int q = 0; q < 4; ++q) {
                float v = acc[mi][ni][q] + bv;
                v = v > 0.f ? v : 0.f;
                Hout[(size_t)(rb + q) * HH + col] = f2bf(v);
            }
        }
    }
}

// ---------------------------------------------------------------------------
// L4 GEMM (N=256, final scatter): proven R5 structure, BM=BN=128, BK=32.
// ---------------------------------------------------------------------------
#define STAGE4(b, kt)                           \
    {                                           \
        const int kb_ = (kt) * 32;              \
        GLDS16(gA0 + kb_, lA0 + (b) * 4096);    \
        GLDS16(gA1 + kb_, lA1 + (b) * 4096);    \
        GLDS16(gB0 + kb_, lB0 + (b) * 4096);    \
        GLDS16(gB1 + kb_, lB1 + (b) * 4096);    \
    }

#define COMPUTE4(b)                                                       \
    {                                                                     \
        bf16x8 af[4], bfr[4];                                             \
        _Pragma("unroll")                                                 \
        for (int i = 0; i < 4; ++i) {                                     \
            af[i]  = *(const bf16x8*)(fA + (b) * 4096 + i * 16 * 32);     \
            bfr[i] = *(const bf16x8*)(fB + (b) * 4096 + i * 16 * 32);     \
        }                                                                 \
        __builtin_amdgcn_s_setprio(1);                                    \
        _Pragma("unroll")                                                 \
        for (int mi = 0; mi < 4; ++mi)                                    \
            _Pragma("unroll")                                             \
            for (int ni = 0; ni < 4; ++ni)                                \
                acc[mi][ni] = __builtin_amdgcn_mfma_f32_16x16x32_bf16(    \
                    af[mi], bfr[ni], acc[mi][ni], 0, 0, 0);               \
        __builtin_amdgcn_s_setprio(0);                                    \
    }

#define WAITV(N)                                                          \
    asm volatile("s_waitcnt vmcnt(" #N ")" ::: "memory");                 \
    __builtin_amdgcn_s_barrier();                                         \
    __builtin_amdgcn_sched_barrier(0);

__global__ __launch_bounds__(256, 3)
void gemm_final_kernel(const u16* __restrict__ Abase, const u16* __restrict__ Wbase,
                       size_t wclass_stride, const float* __restrict__ bias_base,
                       int bias_stride, const int* __restrict__ offsets,
                       const int* __restrict__ rowidx, float* __restrict__ Fout)
{
    __shared__ u16 sA[3 * 128 * 32];
    __shared__ u16 sB[3 * 128 * 32];
    const int tid = threadIdx.x;

    const int bid = blockIdx.x;
    const int wg = (bid & 7) * ((int)gridDim.x >> 3) + (bid >> 3);
    const int m0 = (wg >> 1) * 128;
    const int n0 = (wg & 1) * 128;
    if (m0 >= offsets[CC]) return;
    int c = 0;
    while (m0 >= offsets[c + 1]) ++c;

    const int srow = tid >> 2;
    const int kc8 = (tid & 3) * 8;
    const int sa0 = m0 + srow, sa1 = m0 + srow + 64;
    const u16* gA0 = Abase + (size_t)sa0 * 1024 + kc8;
    const u16* gA1 = Abase + (size_t)sa1 * 1024 + kc8;
    const u16* Wcl = Wbase + (size_t)c * wclass_stride;
    const u16* gB0 = Wcl + (size_t)(n0 + srow) * 1024 + kc8;
    const u16* gB1 = Wcl + (size_t)(n0 + srow + 64) * 1024 + kc8;
    u16* lA0 = sA + tid * 8;
    u16* lA1 = sA + 2048 + tid * 8;
    u16* lB0 = sB + tid * 8;
    u16* lB1 = sB + 2048 + tid * 8;

    const int lane = tid & 63, wv = tid >> 6;
    const int wm = (wv & 1) * 64, wn = (wv >> 1) * 64;
    const int lr = lane & 15, lg = lane >> 4;
    const u16* fA = sA + (wm + lr) * 32 + lg * 8;
    const u16* fB = sB + (wn + lr) * 32 + lg * 8;

    f32x4 acc[4][4];
    #pragma unroll
    for (int i = 0; i < 4; ++i)
        #pragma unroll
        for (int j = 0; j < 4; ++j)
            acc[i][j] = (f32x4){0.f, 0.f, 0.f, 0.f};

    STAGE4(0, 0);
    STAGE4(1, 1);
    for (int kt = 0; kt < 30; kt += 3) {
        WAITV(4);
        STAGE4(2, kt + 2);
        COMPUTE4(0);
        WAITV(4);
        STAGE4(0, kt + 3);
        COMPUTE4(1);
        WAITV(4);
        STAGE4(1, kt + 4);
        COMPUTE4(2);
    }
    WAITV(4);
    COMPUTE4(0);
    WAITV(0);
    COMPUTE4(1);

    const float* bp = bias_base + (size_t)c * bias_stride + n0 + wn + lr;
    #pragma unroll
    for (int ni = 0; ni < 4; ++ni) {
        const float bv = bp[ni * 16];
        const int col = n0 + wn + ni * 16 + lr;
        #pragma unroll
        for (int mi = 0; mi < 4; ++mi) {
            const int rb = m0 + wm + mi * 16 + lg * 4;
            #pragma unroll
            for (int q = 0; q < 4; ++q) {
                const float v = acc[mi][ni][q] + bv;
                const int orow = rowidx[rb + q];
                if (orow >= 0) Fout[(size_t)orow * OO + col] = v;
            }
        }
    }
}

// ---------------------------------------------------------------------------
extern "C" void kernel_launch(void* const* d_in, const int* in_sizes, int n_in,
                              void* d_out, int out_size, void* d_ws, size_t ws_size,
                              hipStream_t stream)
{
    const float* x  = (const float*)d_in[0];
    const float* Wc = (const float*)d_in[1];
    const float* bc = (const float*)d_in[2];
    const float* W1 = (const float*)d_in[3];
    const float* b1 = (const float*)d_in[4];
    const float* W2 = (const float*)d_in[5];
    const float* b2 = (const float*)d_in[6];
    const float* Wo = (const float*)d_in[7];
    const float* bo = (const float*)d_in[8];
    float* out    = (float*)d_out;                 // [B][O]
    float* logits = out + (size_t)BB * OO;         // [B][C]

    char* ws = (char*)d_ws;
    constexpr size_t PADMAX = BB + CC * 256;       // 18432 padded rows max
    constexpr int NLB = BB / 16;                   // 1024 logits blocks
    int* offsets   = (int*)(ws + 0);               // [9]
    int* hist      = (int*)(ws + 64);              // [NLB][8]
    int* bb        = (int*)(ws + 64 + NLB * 32);   // [NLB][8]
    int* class_idx = (int*)(ws + 64 + 2 * NLB * 32);
    int* rowidx    = (int*)((char*)class_idx + (size_t)BB * 4);
    u16* x_bf16    = (u16*)((char*)rowidx + PADMAX * 4);
    u16* hA  = x_bf16 + (size_t)BB * DD;
    u16* hB  = hA + PADMAX * HH;
    u16* W1T = hB + PADMAX * HH;                    // [C][H][D]
    u16* W2T = W1T + (size_t)CC * DD * HH;          // [C][2][H][H]
    u16* WoT = W2T + (size_t)CC * 2 * HH * HH;      // [C][O][H]

    hipMemsetAsync(rowidx, 0xFF, PADMAX * 4, stream);  // pad slots = -1

    transpose_bf16_kernel<<<dim3(32, 32, 8),  256, 0, stream>>>(W1, W1T, DD, HH);
    transpose_bf16_kernel<<<dim3(32, 32, 16), 256, 0, stream>>>(W2, W2T, HH, HH);
    transpose_bf16_kernel<<<dim3(8, 32, 8),   256, 0, stream>>>(Wo, WoT, HH, OO);

    logits_kernel<<<NLB, 256, 0, stream>>>(x, Wc, bc, logits, x_bf16, class_idx, hist);
    scan_kernel<<<1, 256, 0, stream>>>(hist, offsets, bb);
    scatter_kernel<<<BB / 256, 256, 0, stream>>>(class_idx, bb, rowidx);

    constexpr int MT2 = (int)(PADMAX / 256);  // 72 M-tiles (256-row)
    constexpr int MT4 = (int)(PADMAX / 128);  // 144 M-tiles (128-row, L4)
    gemm_kernel<true ><<<dim3(MT2 * 8), 256, 0, stream>>>(
        x_bf16, W1T, (size_t)DD * HH, b1, HH, offsets, rowidx, hA);
    gemm_kernel<false><<<dim3(MT2 * 8), 256, 0, stream>>>(
        hA, W2T, (size_t)2 * HH * HH, b2, 2 * HH, offsets, rowidx, hB);
    gemm_kernel<false><<<dim3(MT2 * 8), 256, 0, stream>>>(
        hB, W2T + (size_t)HH * HH, (size_t)2 * HH * HH, b2 + HH, 2 * HH, offsets, rowidx, hA);
    gemm_final_kernel<<<dim3(MT4 * 2), 256, 0, stream>>>(
        hA, WoT, (size_t)OO * HH, bo, OO, offsets, rowidx, out);
}

// Round 13
// 275.184 us; speedup vs baseline: 1.5236x; 1.5236x over previous
//
#include <hip/hip_runtime.h>
#include <stdint.h>

// Problem constants
#define BB 16384
#define DD 1024
#define HH 1024
#define OO 256
#define CC 8

typedef unsigned short u16;
typedef __attribute__((ext_vector_type(4))) unsigned short u16x4;
typedef __attribute__((ext_vector_type(8))) short bf16x8;
typedef __attribute__((ext_vector_type(4))) float f32x4;

__device__ __forceinline__ u16 f2bf(float f) {
    union { float f; uint32_t u; } v; v.f = f;
    const uint32_t u = v.u;
    return (u16)((u + 0x7FFFu + ((u >> 16) & 1u)) >> 16);  // RNE
}

// async global->LDS, 16B per lane (dest must be wave-uniform base + lane*16)
#define GLDS16(g, l)                                                                   \
    __builtin_amdgcn_global_load_lds((const __attribute__((address_space(1))) void*)(g), \
                                     (__attribute__((address_space(3))) void*)(l), 16, 0, 0)

// ---------------------------------------------------------------------------
// Transpose fp32 [nmat][R][Cc] -> bf16 [nmat][Cc][R]  (W -> W^T, K-contiguous)
// ---------------------------------------------------------------------------
__global__ __launch_bounds__(256)
void transpose_bf16_kernel(const float* __restrict__ src, u16* __restrict__ dst,
                           int R, int Cc)
{
    __shared__ float t[32][33];
    const int tid = threadIdx.x;
    const int mat = blockIdx.z;
    const int r0 = blockIdx.y * 32, c0 = blockIdx.x * 32;
    {
        const int rr = tid >> 3, c4 = (tid & 7) * 4;
        const float4 v = *(const float4*)(src + ((size_t)mat * R + r0 + rr) * Cc + c0 + c4);
        t[rr][c4 + 0] = v.x; t[rr][c4 + 1] = v.y; t[rr][c4 + 2] = v.z; t[rr][c4 + 3] = v.w;
    }
    __syncthreads();
    {
        const int cc = tid >> 3, k4 = (tid & 7) * 4;
        u16x4 o;
        o[0] = f2bf(t[k4 + 0][cc]);
        o[1] = f2bf(t[k4 + 1][cc]);
        o[2] = f2bf(t[k4 + 2][cc]);
        o[3] = f2bf(t[k4 + 3][cc]);
        *(u16x4*)(dst + ((size_t)mat * Cc + c0 + cc) * R + r0 + k4) = o;
    }
}

// ---------------------------------------------------------------------------
// Logits (fp32, exact routing) + x -> bf16 + per-block class histogram.
// ---------------------------------------------------------------------------
__global__ __launch_bounds__(256)
void logits_kernel(const float* __restrict__ x, const float* __restrict__ Wc,
                   const float* __restrict__ bc, float* __restrict__ logits_out,
                   u16* __restrict__ x_bf16, int* __restrict__ class_idx,
                   int* __restrict__ hist)
{
    __shared__ float WcT[CC][DD];  // 32 KB, transposed classifier
    __shared__ int clsarr[16];
    const int tid = threadIdx.x;
    #pragma unroll
    for (int j = 0; j < 8; ++j) {
        const int f = tid + 256 * j;                 // float4 index into Wc [D][C]
        const float4 v = ((const float4*)Wc)[f];
        const int d = f >> 1, c = (f & 1) * 4;       // 4 elems share d (C=8)
        WcT[c + 0][d] = v.x; WcT[c + 1][d] = v.y; WcT[c + 2][d] = v.z; WcT[c + 3][d] = v.w;
    }
    __syncthreads();

    const int lane = tid & 63, wv = tid >> 6;
    const int row0 = blockIdx.x * 16 + wv * 4;

    float acc[4][8];
    #pragma unroll
    for (int r = 0; r < 4; ++r)
        #pragma unroll
        for (int c = 0; c < 8; ++c) acc[r][c] = 0.f;

    #pragma unroll
    for (int p = 0; p < 2; ++p) {
        float4 xv[2][4];
        #pragma unroll
        for (int rr = 0; rr < 2; ++rr) {
            const float4* xr = (const float4*)(x + (size_t)(row0 + 2 * p + rr) * DD);
            #pragma unroll
            for (int j = 0; j < 4; ++j) xv[rr][j] = xr[lane + 64 * j];
        }
        #pragma unroll
        for (int rr = 0; rr < 2; ++rr) {
            u16* xb = x_bf16 + (size_t)(row0 + 2 * p + rr) * DD;
            #pragma unroll
            for (int j = 0; j < 4; ++j) {
                const float4 v = xv[rr][j];
                u16x4 o; o[0] = f2bf(v.x); o[1] = f2bf(v.y); o[2] = f2bf(v.z); o[3] = f2bf(v.w);
                *(u16x4*)(xb + 4 * (lane + 64 * j)) = o;
            }
        }
        #pragma unroll
        for (int j = 0; j < 4; ++j) {
            const int f = lane + 64 * j;
            #pragma unroll
            for (int c = 0; c < 8; ++c) {
                const float4 w = *(const float4*)&WcT[c][4 * f];
                #pragma unroll
                for (int rr = 0; rr < 2; ++rr)
                    acc[2 * p + rr][c] += xv[rr][j].x * w.x + xv[rr][j].y * w.y
                                        + xv[rr][j].z * w.z + xv[rr][j].w * w.w;
            }
        }
    }

    #pragma unroll
    for (int off = 8; off < 64; off <<= 1)
        #pragma unroll
        for (int r = 0; r < 4; ++r)
            #pragma unroll
            for (int c = 0; c < 8; ++c)
                acc[r][c] += __shfl_xor(acc[r][c], off, 64);

    const int cls = lane >> 3;
    const float bcv = bc[cls];
    float s[4];
    #pragma unroll
    for (int r = 0; r < 4; ++r) {
        float v = acc[r][0];
        #pragma unroll
        for (int c = 1; c < 8; ++c) v = (cls == c) ? acc[r][c] : v;
        s[r] = v;
    }
    #pragma unroll
    for (int off = 1; off < 8; off <<= 1)
        #pragma unroll
        for (int r = 0; r < 4; ++r) s[r] += __shfl_xor(s[r], off, 64);
    #pragma unroll
    for (int r = 0; r < 4; ++r) s[r] += bcv;

    #pragma unroll
    for (int r = 0; r < 4; ++r)
        if ((lane & 7) == 0) logits_out[(size_t)(row0 + r) * CC + cls] = s[r];

    int idx[4] = {cls, cls, cls, cls};
    #pragma unroll
    for (int off = 8; off < 64; off <<= 1) {
        #pragma unroll
        for (int r = 0; r < 4; ++r) {
            const float ov = __shfl_xor(s[r], off, 64);
            const int oi = __shfl_xor(idx[r], off, 64);
            const bool take = (ov > s[r]) || (ov == s[r] && oi < idx[r]);
            s[r] = take ? ov : s[r];
            idx[r] = take ? oi : idx[r];
        }
    }
    if (lane == 0) {
        #pragma unroll
        for (int r = 0; r < 4; ++r) {
            class_idx[row0 + r] = idx[r];
            clsarr[wv * 4 + r] = idx[r];
        }
    }
    __syncthreads();
    if (tid < 64) {
        const int myc = (tid < 16) ? clsarr[tid] : -1;
        int h = 0;
        #pragma unroll
        for (int cc = 0; cc < 8; ++cc) {
            const int p = __popcll(__ballot(myc == cc));
            h = (tid == cc) ? p : h;
        }
        if (tid < 8) hist[blockIdx.x * 8 + tid] = h;
    }
}

// ---------------------------------------------------------------------------
// Single-block scan: per-class totals -> padded offsets (128-granular) +
// per-block scatter bases.
// ---------------------------------------------------------------------------
__global__ __launch_bounds__(256)
void scan_kernel(const int* __restrict__ hist, int* __restrict__ offsets,
                 int* __restrict__ bb)
{
    const int t = threadIdx.x, c = t >> 5, g = t & 31;
    int sum = 0;
    #pragma unroll 4
    for (int i = 0; i < 32; ++i) sum += hist[(g * 32 + i) * 8 + c];
    int inc = sum;
    #pragma unroll
    for (int d = 1; d < 32; d <<= 1) {
        const int v = __shfl_up(inc, d, 32);
        if (g >= d) inc += v;
    }
    __shared__ int tot[8], offL[9];
    if (g == 31) tot[c] = inc;
    __syncthreads();
    if (t == 0) {
        int o = 0; offL[0] = 0; offsets[0] = 0;
        #pragma unroll
        for (int c8 = 0; c8 < 8; ++c8) {
            o += (tot[c8] + 127) & ~127;          // pad to 128 (BM granule)
            offL[c8 + 1] = o; offsets[c8 + 1] = o;
        }
    }
    __syncthreads();
    int base = offL[c] + (inc - sum);
    #pragma unroll 4
    for (int i = 0; i < 32; ++i) {
        const int b = g * 32 + i;
        bb[b * 8 + c] = base;
        base += hist[b * 8 + c];
    }
}

// ---------------------------------------------------------------------------
// Scatter row ids into per-class segments — atomic-free via ballot ranking.
// ---------------------------------------------------------------------------
__global__ __launch_bounds__(256)
void scatter_kernel(const int* __restrict__ class_idx, const int* __restrict__ bb,
                    int* __restrict__ rowidx)
{
    const int r = blockIdx.x * 256 + threadIdx.x;
    const int c = class_idx[r];
    const int lane = threadIdx.x & 63;
    const int gl = lane & ~15;
    const unsigned long long before = (1ull << lane) - (1ull << gl);
    int rank = 0;
    #pragma unroll
    for (int cc = 0; cc < 8; ++cc) {
        const unsigned long long m = __ballot(c == cc);
        const int p = __popcll(m & before);
        rank = (c == cc) ? p : rank;
    }
    rowidx[bb[(r >> 4) * 8 + c] + rank] = r;
}

// ---------------------------------------------------------------------------
// R13 = R4 revert (session empirical optimum). BM=BN=128, BK=32, 4 waves
// (64x64 each, acc[4][4]=64 AGPR, ~132 total regs -> 3 blocks/CU). 2-phase
// dbuf, plain __syncthreads. XCD-chunked 1-D grid, n0-inner. T5 setprio.
// Every deviation tried in R5-R12 (counted vmcnt, depth-2/3, role-split,
// BK=64, fat waves, 8-phase, B-to-reg) lost residency or was null.
// ---------------------------------------------------------------------------
#define STAGE(b, kt)                            \
    {                                           \
        const int kb_ = (kt) * 32;              \
        GLDS16(gA0 + kb_, lA0 + (b) * 4096);    \
        GLDS16(gA1 + kb_, lA1 + (b) * 4096);    \
        GLDS16(gB0 + kb_, lB0 + (b) * 4096);    \
        GLDS16(gB1 + kb_, lB1 + (b) * 4096);    \
    }

#define COMPUTE(b)                                                        \
    {                                                                     \
        bf16x8 af[4], bfr[4];                                             \
        _Pragma("unroll")                                                 \
        for (int i = 0; i < 4; ++i) {                                     \
            af[i]  = *(const bf16x8*)(fA + (b) * 4096 + i * 16 * 32);     \
            bfr[i] = *(const bf16x8*)(fB + (b) * 4096 + i * 16 * 32);     \
        }                                                                 \
        _Pragma("unroll")                                                 \
        for (int mi = 0; mi < 4; ++mi)                                    \
            _Pragma("unroll")                                             \
            for (int ni = 0; ni < 4; ++ni)                                \
                acc[mi][ni] = __builtin_amdgcn_mfma_f32_16x16x32_bf16(    \
                    af[mi], bfr[ni], acc[mi][ni], 0, 0, 0);               \
    }

template<int NT_Y, int NSTRIDE, bool GATHER_A, bool RELU, bool FINAL>
__global__ __launch_bounds__(256)
void gemm_kernel(const u16* __restrict__ Abase, const u16* __restrict__ Wbase,
                 size_t wclass_stride, const float* __restrict__ bias_base,
                 int bias_stride, const int* __restrict__ offsets,
                 const int* __restrict__ rowidx, u16* __restrict__ Hout,
                 float* __restrict__ Fout)
{
    __shared__ u16 sA[2 * 128 * 32];   // [buf][row][k] bf16, 2 x 8 KB
    __shared__ u16 sB[2 * 128 * 32];
    const int tid = threadIdx.x;

    // bijective XCD-chunked swizzle (nwg % 8 == 0), n0 inner
    const int bid = blockIdx.x;
    const int wg = (bid & 7) * ((int)gridDim.x >> 3) + (bid >> 3);
    const int m0 = (wg / NT_Y) * 128;
    const int n0 = (wg % NT_Y) * 128;
    if (m0 >= offsets[CC]) return;            // beyond padded total
    int c = 0;
    while (m0 >= offsets[c + 1]) ++c;         // tile -> class (offsets are 128-multiples)

    const int srow = tid >> 2;                // 0..63
    const int kc8 = (tid & 3) * 8;            // k-chunk (8 bf16 = 16B)
    int sa0 = m0 + srow, sa1 = m0 + srow + 64;
    if (GATHER_A) {
        const int g0 = rowidx[sa0]; sa0 = (g0 < 0) ? 0 : g0;
        const int g1 = rowidx[sa1]; sa1 = (g1 < 0) ? 0 : g1;
    }
    const u16* gA0 = Abase + (size_t)sa0 * 1024 + kc8;
    const u16* gA1 = Abase + (size_t)sa1 * 1024 + kc8;
    const u16* Wcl = Wbase + (size_t)c * wclass_stride;
    const u16* gB0 = Wcl + (size_t)(n0 + srow) * 1024 + kc8;
    const u16* gB1 = Wcl + (size_t)(n0 + srow + 64) * 1024 + kc8;
    u16* lA0 = sA + tid * 8;
    u16* lA1 = sA + 2048 + tid * 8;
    u16* lB0 = sB + tid * 8;
    u16* lB1 = sB + 2048 + tid * 8;

    const int lane = tid & 63, wv = tid >> 6;
    const int wm = (wv & 1) * 64, wn = (wv >> 1) * 64;
    const int lr = lane & 15, lg = lane >> 4;
    const u16* fA = sA + (wm + lr) * 32 + lg * 8;
    const u16* fB = sB + (wn + lr) * 32 + lg * 8;

    f32x4 acc[4][4];
    #pragma unroll
    for (int i = 0; i < 4; ++i)
        #pragma unroll
        for (int j = 0; j < 4; ++j)
            acc[i][j] = (f32x4){0.f, 0.f, 0.f, 0.f};

    // prologue: tile 0 into buf 0
    STAGE(0, 0);
    __syncthreads();
    // main: prefetch t+1 into other buf BEFORE computing t
    for (int kt = 0; kt < 31; ++kt) {
        if (kt & 1) { STAGE(0, kt + 1); COMPUTE(1); }
        else        { STAGE(1, kt + 1); COMPUTE(0); }
        __syncthreads();
    }
    COMPUTE(1);   // tile 31

    const float* bp = bias_base + (size_t)c * bias_stride + n0 + wn + lr;
    #pragma unroll
    for (int ni = 0; ni < 4; ++ni) {
        const float bv = bp[ni * 16];
        const int col = n0 + wn + ni * 16 + lr;
        #pragma unroll
        for (int mi = 0; mi < 4; ++mi) {
            const int rb = m0 + wm + mi * 16 + lg * 4;
            #pragma unroll
            for (int q = 0; q < 4; ++q) {
                float v = acc[mi][ni][q] + bv;
                if (RELU) v = v > 0.f ? v : 0.f;
                if (FINAL) {
                    const int orow = rowidx[rb + q];
                    if (orow >= 0) Fout[(size_t)orow * NSTRIDE + col] = v;
                } else {
                    Hout[(size_t)(rb + q) * NSTRIDE + col] = f2bf(v);
                }
            }
        }
    }
}

// ---------------------------------------------------------------------------
extern "C" void kernel_launch(void* const* d_in, const int* in_sizes, int n_in,
                              void* d_out, int out_size, void* d_ws, size_t ws_size,
                              hipStream_t stream)
{
    const float* x  = (const float*)d_in[0];
    const float* Wc = (const float*)d_in[1];
    const float* bc = (const float*)d_in[2];
    const float* W1 = (const float*)d_in[3];
    const float* b1 = (const float*)d_in[4];
    const float* W2 = (const float*)d_in[5];
    const float* b2 = (const float*)d_in[6];
    const float* Wo = (const float*)d_in[7];
    const float* bo = (const float*)d_in[8];
    float* out    = (float*)d_out;                 // [B][O]
    float* logits = out + (size_t)BB * OO;         // [B][C]

    char* ws = (char*)d_ws;
    constexpr size_t PADMAX = BB + CC * 128;       // 17408 padded rows max
    constexpr int NLB = BB / 16;                   // 1024 logits blocks
    int* offsets   = (int*)(ws + 0);               // [9]
    int* hist      = (int*)(ws + 64);              // [NLB][8]
    int* bb        = (int*)(ws + 64 + NLB * 32);   // [NLB][8]
    int* class_idx = (int*)(ws + 64 + 2 * NLB * 32);
    int* rowidx    = (int*)((char*)class_idx + (size_t)BB * 4);
    u16* x_bf16    = (u16*)((char*)rowidx + PADMAX * 4);
    u16* hA  = x_bf16 + (size_t)BB * DD;
    u16* hB  = hA + PADMAX * HH;
    u16* W1T = hB + PADMAX * HH;                    // [C][H][D]
    u16* W2T = W1T + (size_t)CC * DD * HH;          // [C][2][H][H]
    u16* WoT = W2T + (size_t)CC * 2 * HH * HH;      // [C][O][H]

    hipMemsetAsync(rowidx, 0xFF, PADMAX * 4, stream);  // pad slots = -1

    transpose_bf16_kernel<<<dim3(32, 32, 8),  256, 0, stream>>>(W1, W1T, DD, HH);
    transpose_bf16_kernel<<<dim3(32, 32, 16), 256, 0, stream>>>(W2, W2T, HH, HH);
    transpose_bf16_kernel<<<dim3(8, 32, 8),   256, 0, stream>>>(Wo, WoT, HH, OO);

    logits_kernel<<<NLB, 256, 0, stream>>>(x, Wc, bc, logits, x_bf16, class_idx, hist);
    scan_kernel<<<1, 256, 0, stream>>>(hist, offsets, bb);
    scatter_kernel<<<BB / 256, 256, 0, stream>>>(class_idx, bb, rowidx);

    constexpr int MT = BB / 128 + CC;  // 136 M-tiles (covers worst-case padding)
    gemm_kernel<8, HH, true,  true,  false><<<dim3(MT * 8), 256, 0, stream>>>(
        x_bf16, W1T, (size_t)DD * HH, b1, HH, offsets, rowidx, hA, nullptr);
    gemm_kernel<8, HH, false, true,  false><<<dim3(MT * 8), 256, 0, stream>>>(
        hA, W2T, (size_t)2 * HH * HH, b2, 2 * HH, offsets, rowidx, hB, nullptr);
    gemm_kernel<8, HH, false, true,  false><<<dim3(MT * 8), 256, 0, stream>>>(
        hB, W2T + (size_t)HH * HH, (size_t)2 * HH * HH, b2 + HH, 2 * HH, offsets, rowidx, hA, nullptr);
    gemm_kernel<2, OO, false, false, true ><<<dim3(MT * 2), 256, 0, stream>>>(
        hA, WoT, (size_t)OO * HH, bo, OO, offsets, rowidx, nullptr, out);
}